// Round 9
// baseline (176.719 us; speedup 1.0000x reference)
//
#include <hip/hip_runtime.h>

typedef unsigned short u16;
typedef unsigned int u32;
typedef __attribute__((ext_vector_type(8))) short bf16x8;     // 8 bf16 (4 VGPRs)
typedef __attribute__((ext_vector_type(8))) unsigned short u16x8;
typedef __attribute__((ext_vector_type(4))) unsigned short u16x4;
typedef __attribute__((ext_vector_type(4))) float f32x4;

#define GLD_LDS16(g, l)                                                        \
  __builtin_amdgcn_global_load_lds(                                            \
      (const __attribute__((address_space(1))) void*)(g),                      \
      (__attribute__((address_space(3))) void*)(l), 16, 0, 0)
#define VMCNT(n) asm volatile("s_waitcnt vmcnt(" #n ")" ::: "memory")
#define SBAR()                                                                 \
  do {                                                                         \
    __builtin_amdgcn_s_barrier();                                              \
    __builtin_amdgcn_sched_barrier(0);                                         \
  } while (0)

__device__ inline u16 f2b(float f) {
  union { float f; unsigned u; } v; v.f = f;
  unsigned u = v.u + 0x7FFFu + ((v.u >> 16) & 1u);
  return (u16)(u >> 16);
}

__device__ __forceinline__ u32 cvt_pk(float lo, float hi) {
  u32 r;
  asm("v_cvt_pk_bf16_f32 %0, %1, %2" : "=v"(r) : "v"(lo), "v"(hi));
  return r;
}

// ------------------------------------- fused: convert x  +  conv/transpose W
__global__ __launch_bounds__(256) void k_prep(const float* __restrict__ x,
                                              const float* __restrict__ Wq,
                                              const float* __restrict__ Wk,
                                              const float* __restrict__ Wv,
                                              u16* __restrict__ xb,
                                              u16* __restrict__ Wt) {
  __shared__ u16 T[64][72];
  int tid = threadIdx.x;
  int bid = blockIdx.x;
  if (bid < 3072) {
    size_t i = (size_t)bid * 256 + tid;
    const float* src = x + i * 8;
    f32x4 a = *(const f32x4*)(src);
    f32x4 b = *(const f32x4*)(src + 4);
    u16x8 o;
#pragma unroll
    for (int j = 0; j < 4; j++) { o[j] = f2b(a[j]); o[j + 4] = f2b(b[j]); }
    *(u16x8*)(xb + i * 8) = o;
    return;
  }
  int b2 = bid - 3072;                    // 432 = 12 x 12 x 3
  int k0 = (b2 % 12) * 64, n0 = ((b2 / 12) % 12) * 64, m = b2 / 144;
  const float* W = (m == 0) ? Wq : ((m == 1) ? Wk : Wv);
#pragma unroll
  for (int i = 0; i < 4; i++) {
    int idx = tid + i * 256;
    int row = idx >> 4, quad = idx & 15;
    f32x4 v = *(const f32x4*)&W[(size_t)(k0 + row) * 768 + n0 + quad * 4];
    u16x4 pk;
#pragma unroll
    for (int j = 0; j < 4; j++) pk[j] = f2b(v[j]);
    *(u16x4*)&T[row][quad * 4] = pk;
  }
  __syncthreads();
#pragma unroll
  for (int i = 0; i < 2; i++) {
    int idx = tid + i * 256;
    int nr = idx >> 3, chunk = idx & 7;
    u16x8 o;
#pragma unroll
    for (int j = 0; j < 8; j++) o[j] = T[chunk * 8 + j][nr];
    *(u16x8*)&Wt[(size_t)m * 589824 + (size_t)(n0 + nr) * 768 + k0 + chunk * 8] = o;
  }
}

// ------------------------------------------------------------ QKV projection
// Fused GEMM [8192 x 768] @ [768 x 2304]. BM=128, BN=192, BK=32.
// 768 blocks, 8 waves, 3-deep LDS rotation (60KB -> 2 blocks/CU), counted
// per-wave vmcnt. Q scaled by 0.125*log2(e). z==2 (V): transpose+key-permute.

#define STAGE32(kt, buf)                                                       \
  do {                                                                         \
    {                                                                          \
      int od_ = tid * 16;                                                      \
      int r_ = od_ >> 6;                                                       \
      int c_ = (od_ & 63) ^ (((r_ >> 1) & 3) << 4);                            \
      GLD_LDS16(xA + (size_t)r_ * 1536 + (kt) * 64 + c_,                       \
                SB + (buf) * 20480 + od_);                                     \
    }                                                                          \
    {                                                                          \
      int od_ = tid * 16;                                                      \
      int r_ = od_ >> 6;                                                       \
      int c_ = (od_ & 63) ^ (((r_ >> 1) & 3) << 4);                            \
      GLD_LDS16(xB + (size_t)r_ * 1536 + (kt) * 64 + c_,                       \
                SB + (buf) * 20480 + 8192 + od_);                              \
    }                                                                          \
    if (tid < 256) {                                                           \
      int od_ = (512 + tid) * 16;                                              \
      int r_ = od_ >> 6;                                                       \
      int c_ = (od_ & 63) ^ (((r_ >> 1) & 3) << 4);                            \
      GLD_LDS16(xB + (size_t)r_ * 1536 + (kt) * 64 + c_,                       \
                SB + (buf) * 20480 + 8192 + od_);                              \
    }                                                                          \
  } while (0)

#define WVMCNT(a, b)                                                           \
  do {                                                                         \
    if (wfirst < 256) { VMCNT(a); } else { VMCNT(b); }                         \
  } while (0)

__global__ __launch_bounds__(512, 4) void k_gemm_qkv(
    const u16* __restrict__ xb, const u16* __restrict__ Wt,
    const float* __restrict__ bq, const float* __restrict__ bk,
    const float* __restrict__ bv, u16* __restrict__ Qb, u16* __restrict__ Kb,
    u16* __restrict__ VT) {
  extern __shared__ char SB[];  // 61440 B = 3 bufs x (A 8K + B 12K)
  int tid = threadIdx.x, w = tid >> 6, lane = tid & 63;
  int lq = lane & 15, g = lane >> 4;
  int wm = w >> 2, wn = w & 3;
  int wfirst = __builtin_amdgcn_readfirstlane(tid);   // scalar wave id base

  int bid = blockIdx.x;                    // 768 = 8 XCD chunks of 96
  int sw = (bid & 7) * 96 + (bid >> 3);    // bijective (768 % 8 == 0)
  int bm = sw / 12, bn = sw % 12;          // m-major per XCD
  int m0 = bm * 128;
  int z = bn >> 2;                         // 4 n-tiles per matrix (768/192)
  int nz0 = (bn & 3) * 192;

  const char* xA = (const char*)xb + (size_t)m0 * 1536;
  const char* xB = (const char*)Wt + (size_t)z * 1179648 + (size_t)nz0 * 1536;

  f32x4 acc[4][3];
#pragma unroll
  for (int i = 0; i < 4; i++)
#pragma unroll
    for (int j = 0; j < 3; j++) acc[i][j] = (f32x4){0.f, 0.f, 0.f, 0.f};

  int aoff[4], boff[3];
#pragma unroll
  for (int mi = 0; mi < 4; ++mi) {
    int ra = wm * 64 + mi * 16 + lq;
    aoff[mi] = ra * 64 + ((g * 16) ^ (((ra >> 1) & 3) << 4));
  }
#pragma unroll
  for (int nj = 0; nj < 3; ++nj) {
    int rb = wn * 48 + nj * 16 + lq;
    boff[nj] = 8192 + rb * 64 + ((g * 16) ^ (((rb >> 1) & 3) << 4));
  }

  STAGE32(0, 0);
  STAGE32(1, 1);
  WVMCNT(3, 2);
  SBAR();

#pragma unroll
  for (int kt = 0; kt < 24; ++kt) {
    const int cur = kt % 3;
    if (kt < 22) STAGE32(kt + 2, (kt + 2) % 3);
    bf16x8 af[4], bf[3];
#pragma unroll
    for (int mi = 0; mi < 4; ++mi)
      af[mi] = *(const bf16x8*)(SB + cur * 20480 + aoff[mi]);
#pragma unroll
    for (int nj = 0; nj < 3; ++nj)
      bf[nj] = *(const bf16x8*)(SB + cur * 20480 + boff[nj]);
    __builtin_amdgcn_s_setprio(1);
#pragma unroll
    for (int mi = 0; mi < 4; ++mi)
#pragma unroll
      for (int nj = 0; nj < 3; ++nj)
        acc[mi][nj] = __builtin_amdgcn_mfma_f32_16x16x32_bf16(
            af[mi], bf[nj], acc[mi][nj], 0, 0, 0);
    __builtin_amdgcn_s_setprio(0);
    if (kt < 22) {
      WVMCNT(3, 2);
      SBAR();
    } else if (kt == 22) {
      VMCNT(0);
      SBAR();
    }
  }

  const float* bias = (z == 0) ? bq : ((z == 1) ? bk : bv);
  if (z < 2) {
    u16* outp = (z == 0) ? Qb : Kb;
    float scale = (z == 0) ? 0.18033688f : 1.0f;   // Q: 0.125 * log2(e)
#pragma unroll
    for (int nj = 0; nj < 3; ++nj) {
      int col = nz0 + wn * 48 + nj * 16 + lq;
      float bval = bias[col];
      int h = col >> 6, d = col & 63;
#pragma unroll
      for (int mi = 0; mi < 4; ++mi)
#pragma unroll
        for (int r = 0; r < 4; ++r) {
          int tok = m0 + wm * 64 + mi * 16 + g * 4 + r;
          outp[(((size_t)(tok >> 10) * 12 + h) * 1024 + (tok & 1023)) * 64 +
               d] = f2b((acc[mi][nj][r] + bval) * scale);
        }
    }
  } else {
    // V: transpose 128x192 tile via LDS, write VT[bh][d][perm(n)]
    __syncthreads();
    u16* T = (u16*)SB;                     // [192][136] u16 (52 KB)
#pragma unroll
    for (int nj = 0; nj < 3; ++nj) {
      int col = nz0 + wn * 48 + nj * 16 + lq;
      float bval = bias[col];
#pragma unroll
      for (int mi = 0; mi < 4; ++mi) {
        u16x4 pk;
#pragma unroll
        for (int r = 0; r < 4; ++r) pk[r] = f2b(acc[mi][nj][r] + bval);
        *(u16x4*)&T[(wn * 48 + nj * 16 + lq) * 136 + wm * 64 + mi * 16 +
                    g * 4] = pk;
      }
    }
    __syncthreads();
    int bB = m0 >> 10, nn0 = m0 & 1023;
#pragma unroll
    for (int i = 0; i < 6; ++i) {
      int idx = tid + i * 512;
      int row = idx >> 4, ch = idx & 15;
      int col = nz0 + row;
      int h = col >> 6, d = col & 63;
      int base = ((ch >> 3) << 6) | (((ch & 7) >> 2) << 5) | ((ch & 3) << 2);
      u16x4 lo = *(const u16x4*)&T[row * 136 + base];
      u16x4 hi = *(const u16x4*)&T[row * 136 + base + 16];
      u16x8 o8;
      o8[0] = lo[0]; o8[1] = lo[1]; o8[2] = lo[2]; o8[3] = lo[3];
      o8[4] = hi[0]; o8[5] = hi[1]; o8[6] = hi[2]; o8[7] = hi[3];
      *(u16x8*)&VT[((size_t)(bB * 12 + h) * 64 + d) * 1024 + nn0 + ch * 8] = o8;
    }
  }
}

// ---------------------------------------------------------- flash attention
// Round-7 structure (proven) with ONE change: V is read DIRECTLY from global
// (L2-resident; V-staging was pure overhead per m169). K staging, barriers,
// vmcnt rotation, softmax, PV order byte-identical to the passing kernel.
// Direct-V mapping (derived from the staged path's swizzle cancellation):
//   V byte = (dt*16+lq)*2048 + kv*128 + kk*64 + g*16
__device__ __forceinline__ void stage_k(const char* Kg, char* SB, int bufoff,
                                        int kvi, int tid) {
#pragma unroll
  for (int it = 0; it < 2; ++it) {
    int od = (tid + it * 256) * 16;
    int ol = od ^ (((od >> 7) & 7) << 4);           // inverse-swizzled source
    GLD_LDS16(Kg + (size_t)kvi * 8192 + ol, SB + bufoff + od);
  }
}

__global__ __launch_bounds__(256, 3) void k_attn(const u16* __restrict__ Qb,
                                                 const u16* __restrict__ Kb,
                                                 const u16* __restrict__ VT,
                                                 float* __restrict__ out) {
  __shared__ char SB[24576];          // 3 bufs x K 8K

  int tid = threadIdx.x, w = tid >> 6, lane = tid & 63;
  int lq = lane & 15, g = lane >> 4;
  int bh = blockIdx.x, qb = blockIdx.y;
  int b = bh / 12, h = bh % 12;
  const u16* Qh = Qb + (size_t)bh * 65536;
  const char* Kg = (const char*)(Kb + (size_t)bh * 65536);
  const char* Vg = (const char*)(VT + (size_t)bh * 65536);
  int q0 = qb * 128 + w * 32;
  int swz = (lane & 7) << 4;
  int voff = lq * 2048 + g * 16;      // per-lane V base (d-row lq, key byte g*16)

  bf16x8 qf[2][2];
#pragma unroll
  for (int qt = 0; qt < 2; qt++)
#pragma unroll
    for (int kk = 0; kk < 2; kk++)
      qf[qt][kk] = *(const bf16x8*)&Qh[(size_t)(q0 + qt * 16 + lq) * 64 +
                                       kk * 32 + g * 8];

  bf16x8 ones8;
#pragma unroll
  for (int j = 0; j < 8; j++) ones8[j] = (short)0x3F80;   // bf16 1.0

  float m2[2] = {-1e30f, -1e30f};
  f32x4 l2a[2];                        // l sums in C-layout (q = g*4+r)
  f32x4 o[2][4];
#pragma unroll
  for (int qt = 0; qt < 2; qt++) {
    l2a[qt] = (f32x4){0.f, 0.f, 0.f, 0.f};
#pragma unroll
    for (int dt = 0; dt < 4; dt++) o[qt][dt] = (f32x4){0.f, 0.f, 0.f, 0.f};
  }

  stage_k(Kg, SB, 0, 0, tid);
  stage_k(Kg, SB, 8192, 1, tid);

#pragma unroll
  for (int kv = 0; kv < 16; ++kv) {
    if (kv < 15) {
      VMCNT(2);                      // K tile kv landed; kv+1 in flight
    } else {
      VMCNT(0);
    }
    SBAR();
    if (kv <= 13)
      stage_k(Kg, SB, ((kv + 2) % 3) * 8192, kv + 2, tid);

    const char* KsB = SB + (kv % 3) * 8192;

    // ---- S^T = K . Q  (scores in log2 units)
    f32x4 sa[2][4];
    __builtin_amdgcn_s_setprio(1);
#pragma unroll
    for (int t = 0; t < 4; t++) {
      bf16x8 k0 = *(const bf16x8*)(KsB + (((t * 16 + lq) * 128 + g * 16) ^ swz));
      bf16x8 k1 = *(const bf16x8*)(KsB + (((t * 16 + lq) * 128 + 64 + g * 16) ^ swz));
#pragma unroll
      for (int qt = 0; qt < 2; qt++) {
        sa[qt][t] = __builtin_amdgcn_mfma_f32_16x16x32_bf16(
            k0, qf[qt][0], (f32x4){0.f, 0.f, 0.f, 0.f}, 0, 0, 0);
        sa[qt][t] = __builtin_amdgcn_mfma_f32_16x16x32_bf16(
            k1, qf[qt][1], sa[qt][t], 0, 0, 0);
      }
    }
    __builtin_amdgcn_s_setprio(0);

    // ---- online softmax + in-register P
    bf16x8 pa[2][2];                 // [qt][kk]
#pragma unroll
    for (int qt = 0; qt < 2; qt++) {
      float pm = sa[qt][0][0];
#pragma unroll
      for (int t = 0; t < 4; t++)
#pragma unroll
        for (int r = 0; r < 4; r++) pm = fmaxf(pm, sa[qt][t][r]);
      if (!__all(pm <= m2[qt] + 8.0f)) {
        pm = fmaxf(pm, __shfl_xor(pm, 16));
        pm = fmaxf(pm, __shfl_xor(pm, 32));
        float mn = fmaxf(m2[qt], pm);
        float al = __builtin_amdgcn_exp2f(m2[qt] - mn);
        m2[qt] = mn;
        float alr[4];
#pragma unroll
        for (int r = 0; r < 4; r++) alr[r] = __shfl(al, g * 4 + r);
#pragma unroll
        for (int r = 0; r < 4; r++) l2a[qt][r] *= alr[r];
#pragma unroll
        for (int dt = 0; dt < 4; dt++)
#pragma unroll
          for (int r = 0; r < 4; r++) o[qt][dt][r] *= alr[r];
      }
#pragma unroll
      for (int t = 0; t < 4; t++)
#pragma unroll
        for (int r = 0; r < 4; r++)
          sa[qt][t][r] = __builtin_amdgcn_exp2f(sa[qt][t][r] - m2[qt]);

#pragma unroll
      for (int kk = 0; kk < 2; kk++) {
        u32 w0 = cvt_pk(sa[qt][2 * kk][0], sa[qt][2 * kk][1]);
        u32 w1 = cvt_pk(sa[qt][2 * kk][2], sa[qt][2 * kk][3]);
        u32 w2 = cvt_pk(sa[qt][2 * kk + 1][0], sa[qt][2 * kk + 1][1]);
        u32 w3 = cvt_pk(sa[qt][2 * kk + 1][2], sa[qt][2 * kk + 1][3]);
        union { u32 u[4]; bf16x8 v; } cv;
        cv.u[0] = w0; cv.u[1] = w1; cv.u[2] = w2; cv.u[3] = w3;
        pa[qt][kk] = cv.v;
      }
    }

    // ---- O += P . V ; l += P . 1  (V direct from global / L2)
    __builtin_amdgcn_s_setprio(1);
#pragma unroll
    for (int kk = 0; kk < 2; kk++) {
#pragma unroll
      for (int qt = 0; qt < 2; qt++)
        l2a[qt] = __builtin_amdgcn_mfma_f32_16x16x32_bf16(pa[qt][kk], ones8,
                                                          l2a[qt], 0, 0, 0);
#pragma unroll
      for (int dt = 0; dt < 4; dt++) {
        bf16x8 vb = *(const bf16x8*)(Vg + (size_t)dt * 32768 + kv * 128 +
                                     kk * 64 + voff);
#pragma unroll
        for (int qt = 0; qt < 2; qt++)
          o[qt][dt] = __builtin_amdgcn_mfma_f32_16x16x32_bf16(pa[qt][kk], vb,
                                                              o[qt][dt], 0, 0, 0);
      }
    }
    __builtin_amdgcn_s_setprio(0);
  }

  // ---- epilogue: multiply by 1/l (v_rcp; tolerance >> rcp error)
#pragma unroll
  for (int qt = 0; qt < 2; qt++) {
    float inv[4];
#pragma unroll
    for (int r = 0; r < 4; r++) inv[r] = __builtin_amdgcn_rcpf(l2a[qt][r]);
#pragma unroll
    for (int dt = 0; dt < 4; dt++)
#pragma unroll
      for (int r = 0; r < 4; r++) {
        int q = q0 + qt * 16 + g * 4 + r;
        out[((size_t)b * 1024 + q) * 768 + h * 64 + dt * 16 + lq] =
            o[qt][dt][r] * inv[r];
      }
  }
}

// ---------------------------------------------------------------------------
extern "C" void kernel_launch(void* const* d_in, const int* in_sizes, int n_in,
                              void* d_out, int out_size, void* d_ws,
                              size_t ws_size, hipStream_t stream) {
  const float* x  = (const float*)d_in[0];
  const float* Wq = (const float*)d_in[1];
  const float* bq = (const float*)d_in[2];
  const float* Wk = (const float*)d_in[3];
  const float* bk = (const float*)d_in[4];
  const float* Wv = (const float*)d_in[5];
  const float* bv = (const float*)d_in[6];
  float* out = (float*)d_out;

  char* ws = (char*)d_ws;
  u16* xb = (u16*)ws;                       // 12,582,912 B
  u16* Wt = (u16*)(ws + 12582912);          //  3,538,944 B
  u16* Qb = (u16*)(ws + 16121856);          // 12,582,912 B
  u16* Kb = (u16*)(ws + 28704768);
  u16* VT = (u16*)(ws + 41287680);          // V pre-transposed + key-permuted

  hipFuncSetAttribute((const void*)k_gemm_qkv,
                      hipFuncAttributeMaxDynamicSharedMemorySize, 61440);

  k_prep<<<3504, 256, 0, stream>>>(x, Wq, Wk, Wv, xb, Wt);
  k_gemm_qkv<<<768, 512, 61440, stream>>>(xb, Wt, bq, bk, bv, Qb, Kb, VT);
  k_attn<<<dim3(96, 8), 256, 0, stream>>>(Qb, Kb, VT, out);
}